// Round 18
// baseline (131.653 us; speedup 1.0000x reference)
//
#include <hip/hip_runtime.h>
#include <math.h>

#define RED_BLOCKS 256
#define NT 512             // k_h threads
#define GT 1024            // k_gmax threads
#define CCH 16384          // nodes per chunk; ONE direction = 64 KB LDS -> 2 blocks/CU
#define SPLIT 36           // edge slices per (dir, chunk); grid = 2*nch*SPLIT ~= 504
#define ORD_OFF 0x007fffffu  // f2ord(-inf); shifted so 0 == "-inf"/empty
#define SENT 0xFFFFFFFFu   // self-loop sentinel node id (never in any chunk)

// Monotone order-preserving float->uint mapping, shifted so 0 means -inf.
__device__ __forceinline__ unsigned f2ord(float f) {
    unsigned u = __float_as_uint(f);
    u = (u & 0x80000000u) ? ~u : (u | 0x80000000u);
    return u - ORD_OFF;
}
__device__ __forceinline__ float ord2f(unsigned uo) {
    unsigned u = uo + ORD_OFF;
    unsigned v = (u & 0x80000000u) ? (u & 0x7fffffffu) : ~u;
    return __uint_as_float(v);
}

__device__ __forceinline__ void h_row_body(const float* __restrict__ loss,
                                           const float* __restrict__ Ws,
                                           float* __restrict__ h,
                                           unsigned* __restrict__ ordArr,
                                           int n, int blk) {
    int sub = threadIdx.x & 15, r = threadIdx.x >> 4;   // 32 rows per 512-thread block
    int row = blk * (NT / 16) + r;
    if (row >= n) return;
    const float4* f4 = (const float4*)(loss + (size_t)row * 200);
    const float4* W4 = (const float4*)Ws;
    float4 a, w;
    float acc = 0.0f;
    a = f4[sub];      w = W4[sub];      acc += a.x*w.x + a.y*w.y + a.z*w.z + a.w*w.w;
    a = f4[sub + 16]; w = W4[sub + 16]; acc += a.x*w.x + a.y*w.y + a.z*w.z + a.w*w.w;
    a = f4[sub + 32]; w = W4[sub + 32]; acc += a.x*w.x + a.y*w.y + a.z*w.z + a.w*w.w;
    if (sub < 2) { a = f4[48 + sub]; w = W4[48 + sub]; acc += a.x*w.x + a.y*w.y + a.z*w.z + a.w*w.w; }
    #pragma unroll
    for (int off = 8; off > 0; off >>= 1) acc += __shfl_down(acc, off, 16);
    if (sub == 0) { h[row] = acc; ordArr[row] = f2ord(acc); }
}

__global__ void __launch_bounds__(NT) k_h(const float* __restrict__ loss,
                                          const float* __restrict__ Ws,
                                          float* __restrict__ h,
                                          unsigned* __restrict__ ordArr, int n) {
    h_row_body(loss, Ws, h, ordArr, n, blockIdx.x);
}

// Hoisted per-edge gathers (r17 lesson: gathers in the 7-pass loop cost ~30us;
// they are per-EDGE, not per-visit). One pass at FULL occupancy, deep ILP:
// epre[e] = (dst, ord[src]) ; esuc[e] = (src, ord[dst]); self-loop -> SENT.
__global__ void __launch_bounds__(256) k_pack(
        const int* __restrict__ src, const int* __restrict__ dst,
        const unsigned* __restrict__ ordArr,
        uint2* __restrict__ epre, uint2* __restrict__ esuc, int ne) {
    int base = (blockIdx.x * 256 + threadIdx.x) * 8;
    if (base + 7 < ne) {
        int4 s0 = *(const int4*)(src + base);
        int4 s1 = *(const int4*)(src + base + 4);
        int4 d0 = *(const int4*)(dst + base);
        int4 d1 = *(const int4*)(dst + base + 4);
        int ss[8] = { s0.x, s0.y, s0.z, s0.w, s1.x, s1.y, s1.z, s1.w };
        int dd[8] = { d0.x, d0.y, d0.z, d0.w, d1.x, d1.y, d1.z, d1.w };
        unsigned vs[8], vd[8];
        #pragma unroll
        for (int u = 0; u < 8; ++u) vs[u] = ordArr[ss[u]];
        #pragma unroll
        for (int u = 0; u < 8; ++u) vd[u] = ordArr[dd[u]];
        uint2 ep[8], es[8];
        #pragma unroll
        for (int u = 0; u < 8; ++u) {
            bool same = (ss[u] == dd[u]);
            ep[u] = make_uint2(same ? SENT : (unsigned)dd[u], vs[u]);
            es[u] = make_uint2(same ? SENT : (unsigned)ss[u], vd[u]);
        }
        #pragma unroll
        for (int u = 0; u < 8; ++u) epre[base + u] = ep[u];
        #pragma unroll
        for (int u = 0; u < 8; ++u) esuc[base + u] = es[u];
    } else {
        for (int e = base; e < ne; ++e) {
            int s = src[e], d = dst[e];
            bool same = (s == d);
            epre[e] = make_uint2(same ? SENT : (unsigned)d, ordArr[s]);
            esuc[e] = make_uint2(same ? SENT : (unsigned)s, ordArr[d]);
        }
    }
}

// Single-direction chunked max: block (dir, c, sub) streams its slice of the
// packed entries (8B, coalesced, L3-served re-reads), one membership test,
// one masked NON-RETURNING LDS atomicMax. 64KB LDS -> 2 blocks/CU (32
// waves/CU); no gather stage -> pure prefetchable stream. Exact, order-free
// -> bit-deterministic.
__global__ void __launch_bounds__(GT, 8) k_gmax(
        const uint2* __restrict__ entries, unsigned* __restrict__ partials,
        int ne, int nch, int dirbase, int epb) {
    __shared__ unsigned acc[CCH];
    int c = blockIdx.x / SPLIT, sub = blockIdx.x - c * SPLIT;
    int cc = (c >= nch) ? c - nch : c;           // chunk within direction
    const uint2* E = entries;                     // dir encoded by caller slice
    for (int t = threadIdx.x; t < CCH; t += GT) acc[t] = 0u;
    __syncthreads();
    const unsigned clo = (unsigned)cc * CCH;
    int lo = sub * epb, hi = min(lo + epb, ne);
    int i = lo + (int)threadIdx.x * 16;
    for (; i + 15 < hi; i += GT * 16) {
        // 8 independent int4 loads (= 16 uint2 entries) in flight
        int4 p0 = *(const int4*)((const int*)(E + i));
        int4 p1 = *(const int4*)((const int*)(E + i) + 4);
        int4 p2 = *(const int4*)((const int*)(E + i) + 8);
        int4 p3 = *(const int4*)((const int*)(E + i) + 12);
        int4 p4 = *(const int4*)((const int*)(E + i) + 16);
        int4 p5 = *(const int4*)((const int*)(E + i) + 20);
        int4 p6 = *(const int4*)((const int*)(E + i) + 24);
        int4 p7 = *(const int4*)((const int*)(E + i) + 28);
        unsigned nd[16], vv[16];
        nd[0]=(unsigned)p0.x; vv[0]=(unsigned)p0.y; nd[1]=(unsigned)p0.z; vv[1]=(unsigned)p0.w;
        nd[2]=(unsigned)p1.x; vv[2]=(unsigned)p1.y; nd[3]=(unsigned)p1.z; vv[3]=(unsigned)p1.w;
        nd[4]=(unsigned)p2.x; vv[4]=(unsigned)p2.y; nd[5]=(unsigned)p2.z; vv[5]=(unsigned)p2.w;
        nd[6]=(unsigned)p3.x; vv[6]=(unsigned)p3.y; nd[7]=(unsigned)p3.z; vv[7]=(unsigned)p3.w;
        nd[8]=(unsigned)p4.x; vv[8]=(unsigned)p4.y; nd[9]=(unsigned)p4.z; vv[9]=(unsigned)p4.w;
        nd[10]=(unsigned)p5.x; vv[10]=(unsigned)p5.y; nd[11]=(unsigned)p5.z; vv[11]=(unsigned)p5.w;
        nd[12]=(unsigned)p6.x; vv[12]=(unsigned)p6.y; nd[13]=(unsigned)p6.z; vv[13]=(unsigned)p6.w;
        nd[14]=(unsigned)p7.x; vv[14]=(unsigned)p7.y; nd[15]=(unsigned)p7.z; vv[15]=(unsigned)p7.w;
        #pragma unroll
        for (int u = 0; u < 16; ++u) {
            unsigned ul = nd[u] - clo;
            if (ul < CCH) atomicMax(&acc[ul], vv[u]);
        }
    }
    for (int j = i; j < hi; ++j) {   // tail
        uint2 e = E[j];
        unsigned ul = e.x - clo;
        if (ul < CCH) atomicMax(&acc[ul], e.y);
    }
    __syncthreads();
    unsigned* outp = partials + ((size_t)(dirbase + blockIdx.x)) * CCH;
    for (int t = threadIdx.x; t < CCH; t += GT) outp[t] = acc[t];
}

// ---- Fallback: device-scope filtered atomics (pre at [0], suc at [1<<17]) ----
__global__ void k_edges_dev(const int* __restrict__ src, const int* __restrict__ dst,
                            const float* __restrict__ h, unsigned* __restrict__ partials, int ne) {
    int e = blockIdx.x * blockDim.x + threadIdx.x;
    if (e >= ne) return;
    int s = src[e], d = dst[e];
    if (s == d) return;
    unsigned hs = f2ord(h[s]);
    unsigned hd = f2ord(h[d]);
    unsigned* slot0 = &partials[d];
    unsigned* slot1 = &partials[(1 << 17) + s];
    if (*slot0 < hs) atomicMax(slot0, hs);
    if (*slot1 < hd) atomicMax(slot1, hd);
}

// Fold SPLIT partials per (dir, chunk); logit = h + w0*pre + w1*suc; 0 -> 0.0.
// partials layout: [(dir*nch + c)*SPLIT + sub][CCH]
__global__ void k_logit_max(const float* __restrict__ h, const unsigned* __restrict__ partials,
                            const float* __restrict__ Wg, float* __restrict__ logit,
                            float* __restrict__ maxPart, int n, int nch) {
    __shared__ float sm[256];
    float w0 = Wg[0], w1 = Wg[1];
    float m = -INFINITY;
    for (int i = blockIdx.x * 256 + threadIdx.x; i < n; i += 256 * RED_BLOCKS) {
        int c = i / CCH, loc = i - c * CCH;
        const unsigned* pp = partials + ((size_t)c * SPLIT) * CCH + loc;
        const unsigned* sp = partials + ((size_t)(nch + c) * SPLIT) * CCH + loc;
        unsigned p = 0, s = 0;
        #pragma unroll 4
        for (int k = 0; k < SPLIT; ++k) {
            p = max(p, pp[(size_t)k * CCH]);
            s = max(s, sp[(size_t)k * CCH]);
        }
        float pf = p ? ord2f(p) : 0.0f;
        float sf = s ? ord2f(s) : 0.0f;
        float l = h[i] + w0 * pf + w1 * sf;
        logit[i] = l;
        m = fmaxf(m, l);
    }
    sm[threadIdx.x] = m;
    __syncthreads();
    for (int off = 128; off > 0; off >>= 1) {
        if (threadIdx.x < off) sm[threadIdx.x] = fmaxf(sm[threadIdx.x], sm[threadIdx.x + off]);
        __syncthreads();
    }
    if (threadIdx.x == 0) maxPart[blockIdx.x] = sm[0];
}

// Fallback fold (flat pre/suc arrays).
__global__ void k_logit_max_dev(const float* __restrict__ h, const unsigned* __restrict__ partials,
                                const float* __restrict__ Wg, float* __restrict__ logit,
                                float* __restrict__ maxPart, int n) {
    __shared__ float sm[256];
    float w0 = Wg[0], w1 = Wg[1];
    float m = -INFINITY;
    for (int i = blockIdx.x * 256 + threadIdx.x; i < n; i += 256 * RED_BLOCKS) {
        unsigned p = partials[i], s = partials[(1 << 17) + i];
        float pf = p ? ord2f(p) : 0.0f;
        float sf = s ? ord2f(s) : 0.0f;
        float l = h[i] + w0 * pf + w1 * sf;
        logit[i] = l;
        m = fmaxf(m, l);
    }
    sm[threadIdx.x] = m;
    __syncthreads();
    for (int off = 128; off > 0; off >>= 1) {
        if (threadIdx.x < off) sm[threadIdx.x] = fmaxf(sm[threadIdx.x], sm[threadIdx.x + off]);
        __syncthreads();
    }
    if (threadIdx.x == 0) maxPart[blockIdx.x] = sm[0];
}

__global__ void k_exp_sum(const float* __restrict__ logit, const float* __restrict__ maxPart,
                          float* __restrict__ out, float* __restrict__ sumPart, int n) {
    __shared__ float sm[256];
    sm[threadIdx.x] = maxPart[threadIdx.x];
    __syncthreads();
    for (int off = 128; off > 0; off >>= 1) {
        if (threadIdx.x < off) sm[threadIdx.x] = fmaxf(sm[threadIdx.x], sm[threadIdx.x + off]);
        __syncthreads();
    }
    float gmax = sm[0];
    __syncthreads();
    float acc = 0.0f;
    for (int i = blockIdx.x * 256 + threadIdx.x; i < n; i += 256 * RED_BLOCKS) {
        float e = expf(logit[i] - gmax);
        out[i] = e;
        acc += e;
    }
    sm[threadIdx.x] = acc;
    __syncthreads();
    for (int off = 128; off > 0; off >>= 1) {
        if (threadIdx.x < off) sm[threadIdx.x] += sm[threadIdx.x + off];
        __syncthreads();
    }
    if (threadIdx.x == 0) sumPart[blockIdx.x] = sm[0];
}

__global__ void k_norm(const float* __restrict__ sumPart, float* __restrict__ out, int n) {
    __shared__ float sm[256];
    sm[threadIdx.x] = sumPart[threadIdx.x];
    __syncthreads();
    for (int off = 128; off > 0; off >>= 1) {
        if (threadIdx.x < off) sm[threadIdx.x] += sm[threadIdx.x + off];
        __syncthreads();
    }
    float inv = 1.0f / sm[0];
    for (int i = blockIdx.x * 256 + threadIdx.x; i < n; i += 256 * RED_BLOCKS) out[i] *= inv;
}

extern "C" void kernel_launch(void* const* d_in, const int* in_sizes, int n_in,
                              void* d_out, int out_size, void* d_ws, size_t ws_size,
                              hipStream_t stream) {
    const float* loss = (const float*)d_in[0];   // [N, 200]
    const float* Ws   = (const float*)d_in[1];   // [1, 200]
    const float* Wg   = (const float*)d_in[2];   // [1, 2]
    const int* esrc   = (const int*)d_in[3];     // [E]
    const int* edst   = (const int*)d_in[4];     // [E]
    float* out = (float*)d_out;                  // [N]

    const int n  = in_sizes[0] / 200;
    const int ne = in_sizes[3];
    const int Gh = (n + (NT / 16) - 1) / (NT / 16);

    const int nch = (n + CCH - 1) / CCH;                 // 7 @ n=100K
    const int epb = (((ne + SPLIT - 1) / SPLIT) + 15) & ~15;  // 16-aligned

    // ws layout (32-bit words):
    // h[n] | logit[n] | ordArr[n] | maxPart | sumPart |
    // partials[2*nch*SPLIT*CCH] | epre[ne] (uint2) | esuc[ne] (uint2)
    float*    h        = (float*)d_ws;
    float*    logit    = h + n;
    unsigned* ordArr   = (unsigned*)(logit + n);
    float*    maxPart  = (float*)(ordArr + n);
    float*    sumPart  = maxPart + RED_BLOCKS;
    unsigned* partials = (unsigned*)(sumPart + RED_BLOCKS);
    size_t part_w = (size_t)2 * nch * SPLIT * CCH;
    uint2*    epre     = (uint2*)(partials + part_w);
    uint2*    esuc     = epre + ne;
    size_t need = ((size_t)3 * n + 2 * RED_BLOCKS + part_w) * 4 + (size_t)4 * ne * 4;

    k_h<<<Gh, NT, 0, stream>>>(loss, Ws, h, ordArr, n);

    if (need <= ws_size) {
        k_pack<<<(ne + 2047) / 2048, 256, 0, stream>>>(esrc, edst, ordArr, epre, esuc, ne);
        // pre-direction blocks then suc-direction blocks (separate launches share
        // the machine as the first drains; both 2-blocks/CU resident)
        k_gmax<<<nch * SPLIT, GT, 0, stream>>>(epre, partials, ne, nch, 0, epb);
        k_gmax<<<nch * SPLIT, GT, 0, stream>>>(esuc, partials, ne, nch, nch * SPLIT, epb);
        k_logit_max<<<RED_BLOCKS, 256, 0, stream>>>(h, partials, Wg, logit, maxPart, n, nch);
    } else {
        hipMemsetAsync(partials, 0, (size_t)2 * (1 << 17) * 4, stream);
        k_edges_dev<<<(ne + 255) / 256, 256, 0, stream>>>(esrc, edst, h, partials, ne);
        k_logit_max_dev<<<RED_BLOCKS, 256, 0, stream>>>(h, partials, Wg, logit, maxPart, n);
    }

    k_exp_sum<<<RED_BLOCKS, 256, 0, stream>>>(logit, maxPart, out, sumPart, n);
    k_norm<<<RED_BLOCKS, 256, 0, stream>>>(sumPart, out, n);
}